// Round 3
// baseline (414.540 us; speedup 1.0000x reference)
//
#include <hip/hip_runtime.h>

// RegressionWisard predict (centrality='mean')
//   input:  [B=4096, E=8192] int32 bits
//   map:    [E] permutation int32 (identity in the benchmark)
//   counts: [N=512, 65536] int32
//   sums:   [N=512, 65536] float32
//   out:    [B] float32 = nan_to_num(sum(s where c>0) / sum(c where c>0))
//
// R5: R2/R3/R4 all pin near the compulsory traffic floor but at ~1.75 TB/s
// effective on the random 64B table stream -> DRAM-efficiency bound.
// Since ALL addresses are known before any gather, counting-sort each
// neuron's 4096 addresses by table-line (4096 buckets, LDS) and gather in
// ASCENDING order: the DRAM then sees a 63%-dense ascending line sweep per
// 256KB table slice (row-hit dominated) instead of white noise, and the
// 1.58x/line duplicates merge in the wave coalescer.
// Phase A: addr_t[512][4096] u16.  Phase B: sort+gather -> contrib[n][s].
// Phase C: reduce over neurons.  Fallback to the R3 kernel if ws too small.

constexpr int BATCH   = 4096;
constexpr int ENTRY   = 8192;
constexpr int TUP     = 16;
constexpr int NEUR    = ENTRY / TUP;    // 512
constexpr int LINES   = 4096;           // 64B lines per neuron table
constexpr int THREADS = 256;
constexpr int SPLIT   = 2;              // sample halves per neuron (phase B)
constexpr int SB      = BATCH / SPLIT;  // 2048 samples per workgroup
constexpr int EPT     = SB / THREADS;   // 8 elements per thread

typedef int v4i __attribute__((ext_vector_type(4)));

__device__ __forceinline__ int tuple_addr(
    const int* __restrict__ input, const int* __restrict__ map_n,
    int m0, bool contig, int s)
{
    if (contig) {
        const v4i* p = reinterpret_cast<const v4i*>(input + (size_t)s * ENTRY + m0);
        const v4i a0 = __builtin_nontemporal_load(p);
        const v4i a1 = __builtin_nontemporal_load(p + 1);
        const v4i a2 = __builtin_nontemporal_load(p + 2);
        const v4i a3 = __builtin_nontemporal_load(p + 3);
        return ((a0.x & 1) << 15) | ((a0.y & 1) << 14)
             | ((a0.z & 1) << 13) | ((a0.w & 1) << 12)
             | ((a1.x & 1) << 11) | ((a1.y & 1) << 10)
             | ((a1.z & 1) <<  9) | ((a1.w & 1) <<  8)
             | ((a2.x & 1) <<  7) | ((a2.y & 1) <<  6)
             | ((a2.z & 1) <<  5) | ((a2.w & 1) <<  4)
             | ((a3.x & 1) <<  3) | ((a3.y & 1) <<  2)
             | ((a3.z & 1) <<  1) |  (a3.w & 1);
    } else {
        const int* row = input + (size_t)s * ENTRY;
        int a = 0;
        #pragma unroll
        for (int t = 0; t < TUP; ++t) a = (a << 1) | (row[map_n[t]] & 1);
        return a;
    }
}

// ---- Phase A: addr_t[n][s] for all (neuron, sample) ------------------------
// grid: 64 sample-chunks x 8 neuron-chunks; lane = sample, neuron wave-uniform
__global__ __launch_bounds__(THREADS) void wisard_addr(
    const int* __restrict__ input,
    const int* __restrict__ mapping,
    unsigned short* __restrict__ addr_t)   // [NEUR][BATCH]
{
    const int tid  = threadIdx.x;
    const int lane = tid & 63;
    const int w    = tid >> 6;
    const int nch  = blockIdx.x & 7;
    const int sc   = blockIdx.x >> 3;
    const int s    = sc * 64 + lane;
    const int nb   = nch * 64 + w * 16;

    #pragma unroll 4
    for (int i = 0; i < 16; ++i) {
        const int n = __builtin_amdgcn_readfirstlane(nb) + i;
        const int* map_n = mapping + n * TUP;
        const int m0 = map_n[0];
        bool contig = ((m0 & 3) == 0);
        #pragma unroll
        for (int t = 1; t < TUP; ++t) contig &= (map_n[t] == m0 + t);
        const int a = tuple_addr(input, map_n, m0, contig, s);
        addr_t[(size_t)n * BATCH + s] = (unsigned short)a;   // 128B/wave store
    }
}

// ---- Phase B: per (neuron, sample-half): counting-sort by line + gather ----
__global__ __launch_bounds__(THREADS) void wisard_sortgather(
    const unsigned short* __restrict__ addr_t,
    const int*   __restrict__ counts,
    const float* __restrict__ sums,
    float2*      __restrict__ contrib)     // [NEUR][BATCH] (.x=r, .y=bitcast c)
{
    __shared__ unsigned int hist[LINES];       // 16 KB
    __shared__ unsigned int sorted[SB];        // 8 KB
    __shared__ unsigned int ttot[THREADS];     // 1 KB
    __shared__ unsigned int wsum[THREADS / 64];

    const int tid   = threadIdx.x;
    const int lane  = tid & 63;
    const int w     = tid >> 6;
    const int n     = blockIdx.x >> 1;
    const int half  = blockIdx.x & 1;
    const int sbase = half * SB;

    // load my 8 addresses (coalesced u16)
    unsigned int a[EPT];
    #pragma unroll
    for (int j = 0; j < EPT; ++j)
        a[j] = addr_t[(size_t)n * BATCH + sbase + j * THREADS + tid];

    // histogram by line index (addr >> 4)
    #pragma unroll
    for (int j = 0; j < LINES / THREADS; ++j) hist[j * THREADS + tid] = 0u;
    __syncthreads();
    #pragma unroll
    for (int j = 0; j < EPT; ++j) atomicAdd(&hist[a[j] >> 4], 1u);
    __syncthreads();

    // exclusive scan over hist[4096]: serial-16 per thread + wave/block scan
    unsigned int loc[16];
    unsigned int run = 0;
    #pragma unroll
    for (int j = 0; j < 16; ++j) { loc[j] = run; run += hist[tid * 16 + j]; }
    ttot[tid] = run;
    __syncthreads();
    unsigned int v = ttot[tid];
    #pragma unroll
    for (int off = 1; off < 64; off <<= 1) {
        const unsigned int u = __shfl_up(v, off, 64);
        if (lane >= off) v += u;
    }
    if (lane == 63) wsum[w] = v;
    __syncthreads();
    unsigned int woff = 0;
    for (int i = 0; i < w; ++i) woff += wsum[i];
    const unsigned int excl = woff + v - ttot[tid];
    __syncthreads();
    #pragma unroll
    for (int j = 0; j < 16; ++j) hist[tid * 16 + j] = excl + loc[j];
    __syncthreads();

    // scatter into line-sorted order: pack (addr<<12 | sample)
    #pragma unroll
    for (int j = 0; j < EPT; ++j) {
        const unsigned int pos = atomicAdd(&hist[a[j] >> 4], 1u);
        sorted[pos] = (a[j] << 12) | (unsigned int)(sbase + j * THREADS + tid);
    }
    __syncthreads();

    // sorted gather: ascending line order across the wave; all loads issued
    // before any consumption.
    unsigned int pk[EPT];
    int   cv[EPT];
    float sv[EPT];
    #pragma unroll
    for (int j = 0; j < EPT; ++j) pk[j] = sorted[j * THREADS + tid];
    #pragma unroll
    for (int j = 0; j < EPT; ++j) {
        const size_t idx = ((size_t)n << 16) | (pk[j] >> 12);
        cv[j] = counts[idx];
        sv[j] = sums[idx];
    }
    #pragma unroll
    for (int j = 0; j < EPT; ++j) {
        const int sm = (int)(pk[j] & 4095u);
        const bool t = cv[j] > 0;
        float2 o;
        o.x = t ? sv[j] : 0.0f;
        o.y = __int_as_float(t ? cv[j] : 0);
        contrib[(size_t)n * BATCH + sm] = o;
    }
}

// ---- Phase C: reduce over neurons per sample -------------------------------
// grid: 64 blocks; lane = sample, wave w covers neurons [w*128, w*128+128)
__global__ __launch_bounds__(THREADS) void wisard_final(
    const float2* __restrict__ contrib,
    float*        __restrict__ out)
{
    __shared__ float sr [4][64];
    __shared__ int   scn[4][64];
    const int tid  = threadIdx.x;
    const int lane = tid & 63;
    const int w    = tid >> 6;
    const int s    = blockIdx.x * 64 + lane;

    float r = 0.0f; int c = 0;
    #pragma unroll 8
    for (int i = 0; i < NEUR / 4; ++i) {
        const int n = w * (NEUR / 4) + i;
        const float2 vv = contrib[(size_t)n * BATCH + s];   // 512B/wave
        r += vv.x;
        c += __float_as_int(vv.y);
    }
    sr[w][lane] = r; scn[w][lane] = c;
    __syncthreads();
    if (w == 0) {
        r = sr[0][lane] + sr[1][lane] + sr[2][lane] + sr[3][lane];
        c = scn[0][lane] + scn[1][lane] + scn[2][lane] + scn[3][lane];
        out[s] = (c > 0) ? (r / (float)c) : 0.0f;   // nan_to_num(0/0)==0
    }
}

// ---- Fallback (R3): single-kernel direct gather, if workspace too small ----
__global__ __launch_bounds__(THREADS) void wisard_fallback(
    const int*   __restrict__ input,
    const int*   __restrict__ mapping,
    const int*   __restrict__ counts,
    const float* __restrict__ sums,
    float*       __restrict__ out)
{
    __shared__ float s_resp[2][THREADS / 64];
    __shared__ int   s_cnt [2][THREADS / 64];

    const int tid  = threadIdx.x;
    const int lane = tid & 63;
    const int wv   = tid >> 6;
    const int b0   = blockIdx.x * 2;

    int   cv[2][2];
    float sv[2][2];

    #pragma unroll
    for (int k = 0; k < 2; ++k) {
        const int n = tid + k * THREADS;
        const int* map_n = mapping + n * TUP;
        const int m0 = map_n[0];
        bool contig = ((m0 & 3) == 0);
        #pragma unroll
        for (int t = 1; t < TUP; ++t) contig &= (map_n[t] == m0 + t);
        #pragma unroll
        for (int s = 0; s < 2; ++s) {
            const int a = tuple_addr(input, map_n, m0, contig, b0 + s);
            const size_t idx = ((size_t)n << 16) | (unsigned)a;
            cv[s][k] = counts[idx];
            sv[s][k] = sums[idx];
        }
    }

    float resp[2]; int cnt[2];
    #pragma unroll
    for (int s = 0; s < 2; ++s) {
        resp[s] = 0.0f; cnt[s] = 0;
        #pragma unroll
        for (int k = 0; k < 2; ++k) {
            const bool t = cv[s][k] > 0;
            resp[s] += t ? sv[s][k] : 0.0f;
            cnt [s] += t ? cv[s][k] : 0;
        }
    }
    #pragma unroll
    for (int s = 0; s < 2; ++s) {
        float r = resp[s]; int c = cnt[s];
        #pragma unroll
        for (int off = 32; off > 0; off >>= 1) {
            r += __shfl_down(r, off, 64);
            c += __shfl_down(c, off, 64);
        }
        if (lane == 0) { s_resp[s][wv] = r; s_cnt[s][wv] = c; }
    }
    __syncthreads();
    if (tid < 2) {
        float r = 0.0f; int c = 0;
        #pragma unroll
        for (int w = 0; w < THREADS / 64; ++w) { r += s_resp[tid][w]; c += s_cnt[tid][w]; }
        out[b0 + tid] = (c > 0) ? (r / (float)c) : 0.0f;
    }
}

extern "C" void kernel_launch(void* const* d_in, const int* in_sizes, int n_in,
                              void* d_out, int out_size, void* d_ws, size_t ws_size,
                              hipStream_t stream) {
    (void)in_sizes; (void)n_in; (void)out_size;
    const int*   input   = (const int*)d_in[0];
    const int*   mapping = (const int*)d_in[1];
    const int*   counts  = (const int*)d_in[2];
    const float* sums    = (const float*)d_in[3];
    float*       out     = (float*)d_out;

    const size_t contrib_bytes = (size_t)NEUR * BATCH * sizeof(float2); // 16 MB
    const size_t addr_bytes    = (size_t)NEUR * BATCH * sizeof(unsigned short); // 4 MB

    if (ws_size < contrib_bytes + addr_bytes || d_ws == nullptr) {
        wisard_fallback<<<BATCH / 2, THREADS, 0, stream>>>(
            input, mapping, counts, sums, out);
        return;
    }

    float2*         contrib = (float2*)d_ws;
    unsigned short* addr_t  = (unsigned short*)((char*)d_ws + contrib_bytes);

    wisard_addr<<<(BATCH / 64) * 8, THREADS, 0, stream>>>(input, mapping, addr_t);
    wisard_sortgather<<<NEUR * SPLIT, THREADS, 0, stream>>>(
        addr_t, counts, sums, contrib);
    wisard_final<<<BATCH / 64, THREADS, 0, stream>>>(contrib, out);
}

// Round 4
// 390.229 us; speedup vs baseline: 1.0623x; 1.0623x over previous
//
#include <hip/hip_runtime.h>

// RegressionWisard predict (centrality='mean')
//   input:  [B=4096, E=8192] int32 bits
//   map:    [E] permutation int32 (identity in the benchmark)
//   counts: [N=512, 65536] int32
//   sums:   [N=512, 65536] float32
//   out:    [B] float32 = nan_to_num(sum(s where c>0) / sum(c where c>0))
//
// R6: measured across R2-R5, scattered 64B table reads pin at ~1.7-1.9 TB/s
// REGARDLESS of pattern (random / slice-local / sorted-ascending) -> the
// scattered-request path is rate-limited, not DRAM-row limited. So stop
// gathering: stream the ENTIRE table sequentially (256 MB @ ~6 TB/s ~= 43us
// beats 168 MB scattered @ 1.7 TB/s ~= 100us). Per block = 1 neuron:
// counting-sort the 4096 sample addresses by table-line in LDS, sweep the
// 512KB table with dwordx4, serve each line's hits from registers via a
// cndmask-tree select (exactly one hit per sample -> plain LDS store, no
// atomics). Phase A rebuilt sequential (R5's was a hidden 32KB-stride
// scatter, ~82us).

constexpr int BATCH   = 4096;
constexpr int ENTRY   = 8192;
constexpr int TUP     = 16;
constexpr int NEUR    = ENTRY / TUP;    // 512
constexpr int LINES   = 4096;           // 16-entry (64B) lines per table
constexpr int THREADS = 256;

typedef int v4i __attribute__((ext_vector_type(4)));

__device__ __forceinline__ int tuple_addr(
    const int* __restrict__ input, const int* __restrict__ map_n,
    int m0, bool contig, int s)
{
    if (contig) {
        const v4i* p = reinterpret_cast<const v4i*>(input + (size_t)s * ENTRY + m0);
        const v4i a0 = __builtin_nontemporal_load(p);
        const v4i a1 = __builtin_nontemporal_load(p + 1);
        const v4i a2 = __builtin_nontemporal_load(p + 2);
        const v4i a3 = __builtin_nontemporal_load(p + 3);
        return ((a0.x & 1) << 15) | ((a0.y & 1) << 14)
             | ((a0.z & 1) << 13) | ((a0.w & 1) << 12)
             | ((a1.x & 1) << 11) | ((a1.y & 1) << 10)
             | ((a1.z & 1) <<  9) | ((a1.w & 1) <<  8)
             | ((a2.x & 1) <<  7) | ((a2.y & 1) <<  6)
             | ((a2.z & 1) <<  5) | ((a2.w & 1) <<  4)
             | ((a3.x & 1) <<  3) | ((a3.y & 1) <<  2)
             | ((a3.z & 1) <<  1) |  (a3.w & 1);
    } else {
        const int* row = input + (size_t)s * ENTRY;
        int a = 0;
        #pragma unroll
        for (int t = 0; t < TUP; ++t) a = (a << 1) | (row[map_n[t]] & 1);
        return a;
    }
}

// 16-way register select via cndmask tree (no runtime-indexed array ->
// no scratch; rule #20).
__device__ __forceinline__ int sel4(v4i v, int e01) {
    const int ab = (e01 & 1) ? v.y : v.x;
    const int cd = (e01 & 1) ? v.w : v.z;
    return (e01 & 2) ? cd : ab;
}
__device__ __forceinline__ int sel16(v4i v0, v4i v1, v4i v2, v4i v3, int e) {
    const int e2 = e & 3;
    const int a = sel4(v0, e2), b = sel4(v1, e2);
    const int c = sel4(v2, e2), d = sel4(v3, e2);
    const int ab = (e & 4) ? b : a;
    const int cd = (e & 4) ? d : c;
    return (e & 8) ? cd : ab;
}

// ---- Phase A: addr_t[s][n] for all (sample, neuron) ------------------------
// wave = one sample: lane reads its neuron's 64B input chunk -> wave covers
// 4KB contiguous per j-step (fully sequential HBM stream). Stores 128B/wave.
__global__ __launch_bounds__(THREADS) void wisard_addr(
    const int* __restrict__ input,
    const int* __restrict__ mapping,
    unsigned short* __restrict__ addr_t)   // [BATCH][NEUR]
{
    const int lane = threadIdx.x & 63;
    const int w    = threadIdx.x >> 6;
    const int s    = blockIdx.x * 4 + w;

    #pragma unroll 2
    for (int j = 0; j < NEUR / 64; ++j) {          // 8 neuron groups
        const int n = j * 64 + lane;
        const int* map_n = mapping + n * TUP;
        const int m0 = map_n[0];
        bool contig = ((m0 & 3) == 0);
        #pragma unroll
        for (int t = 1; t < TUP; ++t) contig &= (map_n[t] == m0 + t);
        const int a = tuple_addr(input, map_n, m0, contig, s);
        addr_t[(size_t)s * NEUR + n] = (unsigned short)a;
    }
}

// ---- Phase B: per neuron: counting-sort samples by line + stream table -----
__global__ __launch_bounds__(THREADS) void wisard_stream(
    const unsigned short* __restrict__ addr_t,   // [BATCH][NEUR]
    const int*   __restrict__ counts,
    const float* __restrict__ sums,
    float2*      __restrict__ contrib)           // [NEUR][BATCH]
{
    __shared__ unsigned int hist[LINES];     // 16 KB
    __shared__ unsigned int sorted[BATCH];   // 16 KB
    __shared__ float2 acc[BATCH];            // 32 KB (aliased as scan scratch)

    const int tid  = threadIdx.x;
    const int lane = tid & 63;
    const int w    = tid >> 6;
    // XCD-cluster swizzle (assumes round-robin blockIdx%8 -> XCD): XCD x
    // owns neurons [x*64, x*64+64) so neighbor blocks share addr_t lines
    // in their XCD's L2. 512 = 8*64 exact -> bijective.
    const int n = (blockIdx.x & 7) * 64 + (blockIdx.x >> 3);

    // 1. my 16 sample addresses (strided u16; 4MB total, L2-shared per XCD)
    unsigned int a[16];
    #pragma unroll
    for (int j = 0; j < 16; ++j)
        a[j] = addr_t[(size_t)(j * THREADS + tid) * NEUR + n];

    // 2. histogram by table line (addr >> 4)
    #pragma unroll
    for (int j = 0; j < LINES / THREADS; ++j) hist[j * THREADS + tid] = 0u;
    __syncthreads();
    #pragma unroll
    for (int j = 0; j < 16; ++j) atomicAdd(&hist[a[j] >> 4], 1u);
    __syncthreads();

    // 3. exclusive scan of hist[4096] (scratch aliased onto acc)
    unsigned int* ttot = reinterpret_cast<unsigned int*>(acc);   // [256]
    unsigned int* wsum = ttot + THREADS;                         // [4]
    unsigned int loc[16];
    unsigned int run = 0;
    #pragma unroll
    for (int j = 0; j < 16; ++j) { loc[j] = run; run += hist[tid * 16 + j]; }
    ttot[tid] = run;
    __syncthreads();
    unsigned int v = ttot[tid];
    #pragma unroll
    for (int off = 1; off < 64; off <<= 1) {
        const unsigned int u = __shfl_up(v, off, 64);
        if (lane >= off) v += u;
    }
    if (lane == 63) wsum[w] = v;
    __syncthreads();
    unsigned int woff = 0;
    for (int i = 0; i < w; ++i) woff += wsum[i];
    const unsigned int excl = woff + v - run;
    #pragma unroll
    for (int j = 0; j < 16; ++j) hist[tid * 16 + j] = excl + loc[j];
    __syncthreads();

    // 4. scatter into line-sorted order: pack (addr<<12 | sample)
    #pragma unroll
    for (int j = 0; j < 16; ++j) {
        const unsigned int pos = atomicAdd(&hist[a[j] >> 4], 1u);
        sorted[pos] = (a[j] << 12) | (unsigned int)(j * THREADS + tid);
    }
    __syncthreads();
    // hist[L] is now the END offset of bucket L (== start of bucket L+1)

    // 5. zero accumulators (scan scratch is dead now)
    #pragma unroll
    for (int j = 0; j < 16; ++j) acc[j * THREADS + tid] = make_float2(0.0f, 0.0f);
    __syncthreads();

    // 6. stream the FULL table sequentially; serve each line's hits from regs.
    //    Exactly one address per sample -> each acc slot written at most once.
    const size_t tbase = (size_t)n << 16;
    for (int j = 0; j < 16; ++j) {
        const int L = j * THREADS + tid;
        const v4i* cp = reinterpret_cast<const v4i*>(counts + tbase + ((size_t)L << 4));
        const v4i* sp = reinterpret_cast<const v4i*>(
            reinterpret_cast<const int*>(sums) + tbase + ((size_t)L << 4));
        const v4i c0 = __builtin_nontemporal_load(cp);
        const v4i c1 = __builtin_nontemporal_load(cp + 1);
        const v4i c2 = __builtin_nontemporal_load(cp + 2);
        const v4i c3 = __builtin_nontemporal_load(cp + 3);
        const v4i s0 = __builtin_nontemporal_load(sp);
        const v4i s1 = __builtin_nontemporal_load(sp + 1);
        const v4i s2 = __builtin_nontemporal_load(sp + 2);
        const v4i s3 = __builtin_nontemporal_load(sp + 3);
        const unsigned int beg = (L == 0) ? 0u : hist[L - 1];
        const unsigned int end = hist[L];
        for (unsigned int k = beg; k < end; ++k) {
            const unsigned int pk = sorted[k];
            const int e  = (int)((pk >> 12) & 15u);
            const int sm = (int)(pk & 4095u);
            const int cv = sel16(c0, c1, c2, c3, e);
            const int sb = sel16(s0, s1, s2, s3, e);
            if (cv > 0) {
                float2 o;
                o.x = __int_as_float(sb);   // the sums value
                o.y = __int_as_float(cv);   // the count, bitcast
                acc[sm] = o;
            }
        }
    }
    __syncthreads();

    // 7. coalesced writeback (512B per wave instruction)
    #pragma unroll
    for (int j = 0; j < 16; ++j) {
        const int s = j * THREADS + tid;
        contrib[(size_t)n * BATCH + s] = acc[s];
    }
}

// ---- Phase C: reduce over neurons per sample -------------------------------
__global__ __launch_bounds__(THREADS) void wisard_final(
    const float2* __restrict__ contrib,
    float*        __restrict__ out)
{
    __shared__ float sr [4][64];
    __shared__ int   scn[4][64];
    const int tid  = threadIdx.x;
    const int lane = tid & 63;
    const int w    = tid >> 6;
    const int s    = blockIdx.x * 64 + lane;

    float r = 0.0f; int c = 0;
    #pragma unroll 8
    for (int i = 0; i < NEUR / 4; ++i) {
        const int n = w * (NEUR / 4) + i;
        const float2 vv = contrib[(size_t)n * BATCH + s];   // 512B/wave
        r += vv.x;
        c += __float_as_int(vv.y);
    }
    sr[w][lane] = r; scn[w][lane] = c;
    __syncthreads();
    if (w == 0) {
        r = sr[0][lane] + sr[1][lane] + sr[2][lane] + sr[3][lane];
        c = scn[0][lane] + scn[1][lane] + scn[2][lane] + scn[3][lane];
        out[s] = (c > 0) ? (r / (float)c) : 0.0f;   // nan_to_num(0/0)==0
    }
}

// ---- Fallback (R3): single-kernel direct gather, if workspace too small ----
__global__ __launch_bounds__(THREADS) void wisard_fallback(
    const int*   __restrict__ input,
    const int*   __restrict__ mapping,
    const int*   __restrict__ counts,
    const float* __restrict__ sums,
    float*       __restrict__ out)
{
    __shared__ float s_resp[2][THREADS / 64];
    __shared__ int   s_cnt [2][THREADS / 64];

    const int tid  = threadIdx.x;
    const int lane = tid & 63;
    const int wv   = tid >> 6;
    const int b0   = blockIdx.x * 2;

    int   cv[2][2];
    float sv[2][2];

    #pragma unroll
    for (int k = 0; k < 2; ++k) {
        const int n = tid + k * THREADS;
        const int* map_n = mapping + n * TUP;
        const int m0 = map_n[0];
        bool contig = ((m0 & 3) == 0);
        #pragma unroll
        for (int t = 1; t < TUP; ++t) contig &= (map_n[t] == m0 + t);
        #pragma unroll
        for (int s = 0; s < 2; ++s) {
            const int a = tuple_addr(input, map_n, m0, contig, b0 + s);
            const size_t idx = ((size_t)n << 16) | (unsigned)a;
            cv[s][k] = counts[idx];
            sv[s][k] = sums[idx];
        }
    }

    float resp[2]; int cnt[2];
    #pragma unroll
    for (int s = 0; s < 2; ++s) {
        resp[s] = 0.0f; cnt[s] = 0;
        #pragma unroll
        for (int k = 0; k < 2; ++k) {
            const bool t = cv[s][k] > 0;
            resp[s] += t ? sv[s][k] : 0.0f;
            cnt [s] += t ? cv[s][k] : 0;
        }
    }
    #pragma unroll
    for (int s = 0; s < 2; ++s) {
        float r = resp[s]; int c = cnt[s];
        #pragma unroll
        for (int off = 32; off > 0; off >>= 1) {
            r += __shfl_down(r, off, 64);
            c += __shfl_down(c, off, 64);
        }
        if (lane == 0) { s_resp[s][wv] = r; s_cnt[s][wv] = c; }
    }
    __syncthreads();
    if (tid < 2) {
        float r = 0.0f; int c = 0;
        #pragma unroll
        for (int w = 0; w < THREADS / 64; ++w) { r += s_resp[tid][w]; c += s_cnt[tid][w]; }
        out[b0 + tid] = (c > 0) ? (r / (float)c) : 0.0f;
    }
}

extern "C" void kernel_launch(void* const* d_in, const int* in_sizes, int n_in,
                              void* d_out, int out_size, void* d_ws, size_t ws_size,
                              hipStream_t stream) {
    (void)in_sizes; (void)n_in; (void)out_size;
    const int*   input   = (const int*)d_in[0];
    const int*   mapping = (const int*)d_in[1];
    const int*   counts  = (const int*)d_in[2];
    const float* sums    = (const float*)d_in[3];
    float*       out     = (float*)d_out;

    const size_t contrib_bytes = (size_t)NEUR * BATCH * sizeof(float2);         // 16 MB
    const size_t addr_bytes    = (size_t)BATCH * NEUR * sizeof(unsigned short); //  4 MB

    if (ws_size < contrib_bytes + addr_bytes || d_ws == nullptr) {
        wisard_fallback<<<BATCH / 2, THREADS, 0, stream>>>(
            input, mapping, counts, sums, out);
        return;
    }

    float2*         contrib = (float2*)d_ws;
    unsigned short* addr_t  = (unsigned short*)((char*)d_ws + contrib_bytes);

    wisard_addr<<<BATCH / 4, THREADS, 0, stream>>>(input, mapping, addr_t);
    wisard_stream<<<NEUR, THREADS, 0, stream>>>(addr_t, counts, sums, contrib);
    wisard_final<<<BATCH / 64, THREADS, 0, stream>>>(contrib, out);
}